// Round 7
// baseline (6067.173 us; speedup 1.0000x reference)
//
#include <hip/hip_runtime.h>
#include <hip/hip_bf16.h>

#define B_ 2
#define S_ 1024
#define D_ 1024
#define H_ 16
#define L_ 8
#define FF_ 4096
#define V_ 4096
#define COND_ 4
#define DH_ 64
#define N_ (B_*S_)        // 2048 tokens
#define CHUNK 128
#define NC (S_/CHUNK)     // 8 chunks

typedef __attribute__((ext_vector_type(8)))  _Float16 f16x8;
typedef __attribute__((ext_vector_type(4)))  _Float16 f16x4;
typedef __attribute__((ext_vector_type(16))) float    f32x16;

// Split fp32 into fp16 hi + scaled fp16 residual: f ~= h + l*(1/2048).
// Residual scaled by 2^11 to dodge fp16 denormal flush in MFMA.
__device__ __forceinline__ void split_f16(float f, _Float16& h, _Float16& l) {
    _Float16 hh = (_Float16)f;
    l = (_Float16)((f - (float)hh) * 2048.0f);
    h = hh;
}

// ---------------------------------------------------------------------------
// Embedding + positional embedding
// ---------------------------------------------------------------------------
__global__ __launch_bounds__(256) void embed_k(const int* __restrict__ inputs,
                                               const float* __restrict__ emb,
                                               const float* __restrict__ pos,
                                               float* __restrict__ x) {
    int t   = blockIdx.x * 256 + threadIdx.x;   // over N_*256 float4 slots
    int row = t >> 8;                            // token row 0..2047
    int c4  = (t & 255) * 4;                     // column (float4)
    int s   = row & (S_ - 1);
    int idx = inputs[row];
    float4 e = *(const float4*)(emb + (size_t)idx * D_ + c4);
    float4 p = *(const float4*)(pos + (size_t)s * D_ + c4);
    float4 o; o.x = e.x + p.x; o.y = e.y + p.y; o.z = e.z + p.z; o.w = e.w + p.w;
    *(float4*)(x + (size_t)row * D_ + c4) = o;
}

// ---------------------------------------------------------------------------
// RoPE cos/sin tables: cosT[s*32+j] = cos(s * 10000^(-2j/64)), j in [0,32)
// ---------------------------------------------------------------------------
__global__ __launch_bounds__(256) void ropetab_k(float* __restrict__ cosT,
                                                 float* __restrict__ sinT) {
    int t = blockIdx.x * 256 + threadIdx.x;     // S_*32 = 32768 entries
    int s = t >> 5, j = t & 31;
    float ex   = (float)(2 * j) / (float)DH_;
    float invf = powf(10000.0f, -ex);
    float fr   = (float)s * invf;
    float sn, cs;
    sincosf(fr, &sn, &cs);
    cosT[t] = cs; sinT[t] = sn;
}

// ---------------------------------------------------------------------------
// In-place RoPE + (elu+1) feature map on q and k; k additionally masked.
// ---------------------------------------------------------------------------
__global__ __launch_bounds__(256) void rope_elu_k(float* __restrict__ q,
                                                  float* __restrict__ k,
                                                  const float* __restrict__ cosT,
                                                  const float* __restrict__ sinT,
                                                  const int* __restrict__ mask) {
    int t   = blockIdx.x * 256 + threadIdx.x;   // N_*H_*32 = 1048576
    int j   = t & 31;
    int h   = (t >> 5) & (H_ - 1);
    int row = t >> 9;                            // / (H_*32)
    int s   = row & (S_ - 1);
    float c  = cosT[s * 32 + j];
    float sn = sinT[s * 32 + j];
    size_t base = (size_t)row * D_ + h * DH_;
    {
        float t1 = q[base + j], t2 = q[base + j + 32];
        float r1 = t1 * c - t2 * sn;
        float r2 = t2 * c + t1 * sn;
        q[base + j]      = (r1 > 0.f) ? r1 + 1.f : expf(r1);
        q[base + j + 32] = (r2 > 0.f) ? r2 + 1.f : expf(r2);
    }
    {
        float m  = (float)mask[row];
        float t1 = k[base + j], t2 = k[base + j + 32];
        float r1 = t1 * c - t2 * sn;
        float r2 = t2 * c + t1 * sn;
        float f1 = (r1 > 0.f) ? r1 + 1.f : expf(r1);
        float f2 = (r2 > 0.f) ? r2 + 1.f : expf(r2);
        k[base + j]      = f1 * m;
        k[base + j + 32] = f2 * m;
    }
}

// ---------------------------------------------------------------------------
// Linear attention, chunked scan (fp32, small cost).
// Kernel A: per (b,h,chunk): Sc = Kf_c^T V_c (64x64), ks = sum kf.
// ---------------------------------------------------------------------------
__global__ __launch_bounds__(256) void attn_chunksum_k(const float* __restrict__ kf,
                                                       const float* __restrict__ v,
                                                       float* __restrict__ cs,
                                                       float* __restrict__ ksc) {
    int bhc = blockIdx.x;
    int bh  = bhc / NC, c = bhc % NC;
    int b   = bh / H_,  h = bh % H_;
    int row0 = b * S_ + c * CHUNK;
    int col0 = h * DH_;
    int t = threadIdx.x;
    int j = t & 63, ib = t >> 6;
    __shared__ float kts[16][64];
    __shared__ float vts[16][64];
    float acc[16] = {};
    float ksacc = 0.f;
    int lr = t >> 4;
    int lc = (t & 15) * 4;
    for (int st = 0; st < CHUNK / 16; ++st) {
        const float* kp = kf + (size_t)(row0 + st * 16 + lr) * D_ + col0 + lc;
        const float* vp = v  + (size_t)(row0 + st * 16 + lr) * D_ + col0 + lc;
        *(float4*)&kts[lr][lc] = *(const float4*)kp;
        *(float4*)&vts[lr][lc] = *(const float4*)vp;
        __syncthreads();
        #pragma unroll
        for (int r = 0; r < 16; ++r) {
            float vv = vts[r][j];
            #pragma unroll
            for (int ii = 0; ii < 16; ++ii)
                acc[ii] = fmaf(kts[r][ib * 16 + ii], vv, acc[ii]);
            if (t < 64) ksacc += kts[r][t];
        }
        __syncthreads();
    }
    float* csp = cs + (size_t)bhc * (DH_ * DH_);
    #pragma unroll
    for (int ii = 0; ii < 16; ++ii)
        csp[(ib * 16 + ii) * 64 + j] = acc[ii];
    if (t < 64) ksc[(size_t)bhc * 64 + t] = ksacc;
}

// Kernel B: exclusive prefix over chunks for each (b,h).
__global__ __launch_bounds__(256) void attn_prefix_k(const float* __restrict__ cs,
                                                     const float* __restrict__ ksc,
                                                     float* __restrict__ sb,
                                                     float* __restrict__ ksb) {
    int bh = blockIdx.x;
    int t  = threadIdx.x;
    float acc[16] = {};
    for (int c = 0; c < NC; ++c) {
        size_t base = ((size_t)bh * NC + c) * (DH_ * DH_);
        #pragma unroll
        for (int k2 = 0; k2 < 16; ++k2) {
            int e = t + k2 * 256;
            sb[base + e] = acc[k2];
            acc[k2] += cs[base + e];
        }
    }
    if (t < 64) {
        float ka = 0.f;
        for (int c = 0; c < NC; ++c) {
            size_t base = ((size_t)bh * NC + c) * 64;
            ksb[base + t] = ka;
            ka += ksc[base + t];
        }
    }
}

// Kernel C: per (b,h,chunk): a = (Qf@state + tril(Qf Kf^T)@V) / (z + 1e-6)
__global__ __launch_bounds__(256) void attn_out_k(const float* __restrict__ qf,
                                                  const float* __restrict__ kf,
                                                  const float* __restrict__ v,
                                                  const float* __restrict__ sb,
                                                  const float* __restrict__ ksb,
                                                  float* __restrict__ a) {
    int bhc = blockIdx.x;
    int bh  = bhc / NC, c = bhc % NC;
    int b   = bh / H_,  h = bh % H_;
    int row0 = b * S_ + c * CHUNK;
    int col0 = h * DH_;
    int t  = threadIdx.x;
    int s  = t >> 1;
    int jh = t & 1;
    __shared__ float sbs[64][64];
    __shared__ float ktile[32][64];
    __shared__ float vtile[32][64];
    __shared__ float ksbs[64];
    {
        const float4* sp = (const float4*)(sb + (size_t)bhc * (DH_ * DH_));
        float4* dp = (float4*)&sbs[0][0];
        #pragma unroll
        for (int k2 = 0; k2 < 4; ++k2) dp[t + k2 * 256] = sp[t + k2 * 256];
        if (t < 64) ksbs[t] = ksb[(size_t)bhc * 64 + t];
    }
    float qreg[64];
    {
        const float* qp = qf + (size_t)(row0 + s) * D_ + col0;
        #pragma unroll
        for (int i = 0; i < 64; i += 4)
            *(float4*)&qreg[i] = *(const float4*)(qp + i);
    }
    __syncthreads();
    float nacc[32] = {};
    float zacc = 0.f;
    #pragma unroll 4
    for (int i = 0; i < 64; ++i) {
        float qv = qreg[i];
        zacc = fmaf(qv, ksbs[i], zacc);
        const float4* srow = (const float4*)&sbs[i][jh * 32];
        #pragma unroll
        for (int jq = 0; jq < 8; ++jq) {
            float4 sv = srow[jq];
            nacc[jq * 4 + 0] = fmaf(qv, sv.x, nacc[jq * 4 + 0]);
            nacc[jq * 4 + 1] = fmaf(qv, sv.y, nacc[jq * 4 + 1]);
            nacc[jq * 4 + 2] = fmaf(qv, sv.z, nacc[jq * 4 + 2]);
            nacc[jq * 4 + 3] = fmaf(qv, sv.w, nacc[jq * 4 + 3]);
        }
    }
    int lr = t >> 3;
    int lc = (t & 7) * 8;
    for (int tt = 0; tt < 4; ++tt) {
        const float* kp = kf + (size_t)(row0 + tt * 32 + lr) * D_ + col0 + lc;
        const float* vp = v  + (size_t)(row0 + tt * 32 + lr) * D_ + col0 + lc;
        *(float4*)&ktile[lr][lc]     = *(const float4*)kp;
        *(float4*)&ktile[lr][lc + 4] = *(const float4*)(kp + 4);
        *(float4*)&vtile[lr][lc]     = *(const float4*)vp;
        *(float4*)&vtile[lr][lc + 4] = *(const float4*)(vp + 4);
        __syncthreads();
        int tmax = s - tt * 32; if (tmax > 31) tmax = 31;
        for (int tr = 0; tr <= tmax; ++tr) {
            float sc = 0.f;
            const float4* krow = (const float4*)&ktile[tr][0];
            #pragma unroll
            for (int iq = 0; iq < 16; ++iq) {
                float4 kv4 = krow[iq];
                sc = fmaf(qreg[iq * 4 + 0], kv4.x, sc);
                sc = fmaf(qreg[iq * 4 + 1], kv4.y, sc);
                sc = fmaf(qreg[iq * 4 + 2], kv4.z, sc);
                sc = fmaf(qreg[iq * 4 + 3], kv4.w, sc);
            }
            zacc += sc;
            const float4* vrow = (const float4*)&vtile[tr][jh * 32];
            #pragma unroll
            for (int jq = 0; jq < 8; ++jq) {
                float4 vv4 = vrow[jq];
                nacc[jq * 4 + 0] = fmaf(sc, vv4.x, nacc[jq * 4 + 0]);
                nacc[jq * 4 + 1] = fmaf(sc, vv4.y, nacc[jq * 4 + 1]);
                nacc[jq * 4 + 2] = fmaf(sc, vv4.z, nacc[jq * 4 + 2]);
                nacc[jq * 4 + 3] = fmaf(sc, vv4.w, nacc[jq * 4 + 3]);
            }
        }
        __syncthreads();
    }
    float zf = 1.0f / (zacc + 1e-6f);
    float* ap = a + (size_t)(row0 + s) * D_ + col0 + jh * 32;
    #pragma unroll
    for (int jq = 0; jq < 8; ++jq) {
        float4 o;
        o.x = nacc[jq * 4 + 0] * zf;
        o.y = nacc[jq * 4 + 1] * zf;
        o.z = nacc[jq * 4 + 2] * zf;
        o.w = nacc[jq * 4 + 3] * zf;
        *(float4*)(ap + jq * 4) = o;
    }
}

// ---------------------------------------------------------------------------
// Conditional LayerNorm
// ---------------------------------------------------------------------------
__global__ __launch_bounds__(256) void cln_k(const float* __restrict__ in,
                                             float* __restrict__ out,
                                             const float* __restrict__ g,
                                             const float* __restrict__ bta,
                                             const int* __restrict__ cond) {
    int row = blockIdx.x;
    int b   = row >> 10;
    int cd  = cond[b];
    int t   = threadIdx.x;
    const float* ip = in + (size_t)row * D_;
    float4 vv = *(const float4*)(ip + t * 4);
    float sum = vv.x + vv.y + vv.z + vv.w;
    float sq  = vv.x * vv.x + vv.y * vv.y + vv.z * vv.z + vv.w * vv.w;
    __shared__ float s1[256], s2[256];
    s1[t] = sum; s2[t] = sq;
    __syncthreads();
    for (int st = 128; st > 0; st >>= 1) {
        if (t < st) { s1[t] += s1[t + st]; s2[t] += s2[t + st]; }
        __syncthreads();
    }
    float mu  = s1[0] * (1.0f / D_);
    float var = s2[0] * (1.0f / D_) - mu * mu;
    float rs  = rsqrtf(var + 1e-5f);
    float4 gv = *(const float4*)(g   + (size_t)cd * D_ + t * 4);
    float4 bv = *(const float4*)(bta + (size_t)cd * D_ + t * 4);
    float4 o;
    o.x = (vv.x - mu) * rs * gv.x + bv.x;
    o.y = (vv.y - mu) * rs * gv.y + bv.y;
    o.z = (vv.z - mu) * rs * gv.z + bv.z;
    o.w = (vv.w - mu) * rs * gv.w + bv.w;
    *(float4*)(out + (size_t)row * D_ + t * 4) = o;
}

// ---------------------------------------------------------------------------
// Split-fp16 MFMA GEMM: C = A(MxK fp32) @ B(KxN fp32) + bias [+gelu | +resid]
// A,B split on the fly into fp16 hi + 2^11-scaled fp16 residual.
// acc1 += Ah*Bh ; acc2 += Ah*Bl' + Al'*Bh ; C = acc1 + acc2/2048.
// Tile 128x128, BK=32, 256 threads = 4 waves, each wave 64x64 via 2x2
// v_mfma_f32_32x32x16_f16 fragments. LDS k-slots XOR-swizzled by (row&3).
// Audit r3: k-placement symmetric A/B; swizzle involution verified;
// C/D decode = m74/m101 mapping; no fp16 overflow at this net's scales.
// Audit r5: B-staging k-coverage & slot algebra re-verified end-to-end.
// Audit r6: B-staging is per-instruction coalesced (fixed j => lane-contig);
// A-staging ~2x line over-fetch, L2-absorbed — revisit only if counters rank it.
// ---------------------------------------------------------------------------
#define EPI_BIAS 0
#define EPI_BIAS_GELU 1
#define EPI_BIAS_RES 2

__device__ __forceinline__ float gelu_f(float v) {
    float u = 0.7978845608028654f * (v + 0.044715f * v * v * v);
    return 0.5f * v * (1.0f + tanhf(u));
}

template<int EPI>
__global__ __launch_bounds__(256) void mgemm_k(const float* __restrict__ A,
                                               const float* __restrict__ Bw,
                                               const float* __restrict__ bias,
                                               const float* __restrict__ resid,
                                               float* __restrict__ C,
                                               int M, int N, int K) {
    __shared__ __attribute__((aligned(16))) _Float16 Ah[128 * 32];
    __shared__ __attribute__((aligned(16))) _Float16 Al[128 * 32];
    __shared__ __attribute__((aligned(16))) _Float16 Bh[128 * 32];
    __shared__ __attribute__((aligned(16))) _Float16 Bl[128 * 32];
    int tid = threadIdx.x;
    int l   = tid & 63;
    int w   = tid >> 6;
    int wr  = w >> 1, wc = w & 1;
    int lg  = l >> 5;
    int l31 = l & 31;
    int row0 = blockIdx.y * 128, col0 = blockIdx.x * 128;

    f32x16 acc1[2][2] = {};
    f32x16 acc2[2][2] = {};

    // staging assignments
    int ra  = tid >> 1;            // A row 0..127
    int kcb = (tid & 1) * 16;      // A k-chunk base {0,16}
    int cb  = tid & 127;           // B col 0..127
    int kh  = (tid >> 7) * 16;     // B k-half base {0,16}

    const float* ap0 = A  + (size_t)(row0 + ra) * K + kcb;
    const float* bp0 = Bw + (size_t)kh * N + col0 + cb;

    for (int k0 = 0; k0 < K; k0 += 32) {
        // ---- stage A (fp32 -> fp16 hi/lo, swizzled) ----
        {
            const float* ap = ap0 + k0;
            #pragma unroll
            for (int i = 0; i < 4; ++i) {
                float4 av = *(const float4*)(ap + i * 4);
                _Float16 h0, h1, h2, h3, q0, q1, q2, q3;
                split_f16(av.x, h0, q0); split_f16(av.y, h1, q1);
                split_f16(av.z, h2, q2); split_f16(av.w, h3, q3);
                int kk  = kcb + i * 4;
                int idx = ra * 32 + (((kk >> 3) ^ (ra & 3)) << 3) + (kk & 7);
                f16x4 hv = {h0, h1, h2, h3};
                f16x4 lv = {q0, q1, q2, q3};
                *(f16x4*)&Ah[idx] = hv;
                *(f16x4*)&Al[idx] = lv;
            }
        }
        // ---- stage B (transpose to [col][k], fp32 -> fp16 hi/lo, swizzled) ----
        {
            const float* bp = bp0 + (size_t)k0 * N;
            _Float16 hb[16], lb[16];
            #pragma unroll
            for (int j = 0; j < 16; ++j)
                split_f16(bp[(size_t)j * N], hb[j], lb[j]);
            #pragma unroll
            for (int i = 0; i < 2; ++i) {
                int slot = (kh >> 3) + i;
                int idx  = cb * 32 + ((slot ^ (cb & 3)) << 3);
                f16x8 hv = {hb[i*8+0], hb[i*8+1], hb[i*8+2], hb[i*8+3],
                            hb[i*8+4], hb[i*8+5], hb[i*8+6], hb[i*8+7]};
                f16x8 lv = {lb[i*8+0], lb[i*8+1], lb[i*8+2], lb[i*8+3],
                            lb[i*8+4], lb[i*8+5], lb[i*8+6], lb[i*8+7]};
                *(f16x8*)&Bh[idx] = hv;
                *(f16x8*)&Bl[idx] = lv;
            }
        }
        __syncthreads();
        // ---- compute: 2 K-sub-steps of 16, 2x2 fragments, 3 products ----
        #pragma unroll
        for (int ks = 0; ks < 2; ++ks) {
            f16x8 fah[2], fal[2], fbh[2], fbl[2];
            #pragma unroll
            for (int mi = 0; mi < 2; ++mi) {
                int r   = wr * 64 + mi * 32 + l31;
                int idx = r * 32 + ((((ks << 1) + lg) ^ (r & 3)) << 3);
                fah[mi] = *(const f16x8*)&Ah[idx];
                fal[mi] = *(const f16x8*)&Al[idx];
            }
            #pragma unroll
            for (int ni = 0; ni < 2; ++ni) {
                int c   = wc * 64 + ni * 32 + l31;
                int idx = c * 32 + ((((ks << 1) + lg) ^ (c & 3)) << 3);
                fbh[ni] = *(const f16x8*)&Bh[idx];
                fbl[ni] = *(const f16x8*)&Bl[idx];
            }
            #pragma unroll
            for (int mi = 0; mi < 2; ++mi)
                #pragma unroll
                for (int ni = 0; ni < 2; ++ni) {
                    acc1[mi][ni] = __builtin_amdgcn_mfma_f32_32x32x16_f16(
                        fah[mi], fbh[ni], acc1[mi][ni], 0, 0, 0);
                    acc2[mi][ni] = __builtin_amdgcn_mfma_f32_32x32x16_f16(
                        fah[mi], fbl[ni], acc2[mi][ni], 0, 0, 0);
                    acc2[mi][ni] = __builtin_amdgcn_mfma_f32_32x32x16_f16(
                        fal[mi], fbh[ni], acc2[mi][ni], 0, 0, 0);
                }
        }
        __syncthreads();
    }
    // ---- epilogue: C/D layout col=lane&31, row=(g&3)+8*(g>>2)+4*(lane>>5) ----
    #pragma unroll
    for (int mi = 0; mi < 2; ++mi)
        #pragma unroll
        for (int ni = 0; ni < 2; ++ni) {
            int c  = col0 + wc * 64 + ni * 32 + l31;
            float bi = bias[c];
            #pragma unroll
            for (int g = 0; g < 16; ++g) {
                int rr = (g & 3) + ((g >> 2) << 3) + (lg << 2);
                int r  = row0 + wr * 64 + mi * 32 + rr;
                float v = acc1[mi][ni][g] + acc2[mi][ni][g] * 4.8828125e-4f + bi;
                if (EPI == EPI_BIAS_GELU) v = gelu_f(v);
                if (EPI == EPI_BIAS_RES)  v += resid[(size_t)r * N + c];
                C[(size_t)r * N + c] = v;
            }
        }
}

// ---------------------------------------------------------------------------
// Gumbel argmax one-hot
// ---------------------------------------------------------------------------
__global__ __launch_bounds__(256) void gumbel_k(const float* __restrict__ out,
                                                const float* __restrict__ u,
                                                const float* __restrict__ inv_temp_p,
                                                float* __restrict__ og) {
    int row = blockIdx.x;
    int t   = threadIdx.x;
    float it = inv_temp_p[0];
    const float* op = out + (size_t)row * V_;
    const float* up = u   + (size_t)row * V_;
    float best = -3.4e38f;
    int   bidx = V_;
    #pragma unroll
    for (int k2 = 0; k2 < 4; ++k2) {
        int e = (t + k2 * 256) * 4;
        float4 ov = *(const float4*)(op + e);
        float4 uv = *(const float4*)(up + e);
        float l0 = (ov.x + (-logf(-logf(uv.x + 1e-9f) + 1e-9f))) * it;
        float l1 = (ov.y + (-logf(-logf(uv.y + 1e-9f) + 1e-9f))) * it;
        float l2 = (ov.z + (-logf(-logf(uv.z + 1e-9f) + 1e-9f))) * it;
        float l3 = (ov.w + (-logf(-logf(uv.w + 1e-9f) + 1e-9f))) * it;
        if (l0 > best || (l0 == best && e + 0 < bidx)) { best = l0; bidx = e + 0; }
        if (l1 > best || (l1 == best && e + 1 < bidx)) { best = l1; bidx = e + 1; }
        if (l2 > best || (l2 == best && e + 2 < bidx)) { best = l2; bidx = e + 2; }
        if (l3 > best || (l3 == best && e + 3 < bidx)) { best = l3; bidx = e + 3; }
    }
    __shared__ float rv[256];
    __shared__ int   ri[256];
    rv[t] = best; ri[t] = bidx;
    __syncthreads();
    for (int st = 128; st > 0; st >>= 1) {
        if (t < st) {
            float ov = rv[t + st]; int oi = ri[t + st];
            if (ov > rv[t] || (ov == rv[t] && oi < ri[t])) { rv[t] = ov; ri[t] = oi; }
        }
        __syncthreads();
    }
    int amax = ri[0];
    float* ogp = og + (size_t)row * V_;
    #pragma unroll
    for (int k2 = 0; k2 < 4; ++k2) {
        int e = (t + k2 * 256) * 4;
        float4 z;
        z.x = (amax == e + 0) ? 1.0f : 0.0f;
        z.y = (amax == e + 1) ? 1.0f : 0.0f;
        z.z = (amax == e + 2) ? 1.0f : 0.0f;
        z.w = (amax == e + 3) ? 1.0f : 0.0f;
        *(float4*)(ogp + e) = z;
    }
}

// ---------------------------------------------------------------------------
static void launch_gemm(int epi, const float* A, const float* Bw, const float* bias,
                        const float* resid, float* C, int M, int N, int K,
                        hipStream_t st) {
    dim3 g(N / 128, M / 128), blk(256);
    if (epi == EPI_BIAS)
        mgemm_k<EPI_BIAS><<<g, blk, 0, st>>>(A, Bw, bias, resid, C, M, N, K);
    else if (epi == EPI_BIAS_GELU)
        mgemm_k<EPI_BIAS_GELU><<<g, blk, 0, st>>>(A, Bw, bias, resid, C, M, N, K);
    else
        mgemm_k<EPI_BIAS_RES><<<g, blk, 0, st>>>(A, Bw, bias, resid, C, M, N, K);
}

extern "C" void kernel_launch(void* const* d_in, const int* in_sizes, int n_in,
                              void* d_out, int out_size, void* d_ws, size_t ws_size,
                              hipStream_t stream) {
    const int*   inputs    = (const int*)d_in[0];
    const int*   cond      = (const int*)d_in[1];
    const int*   mask      = (const int*)d_in[2];
    const float* gumbel_u  = (const float*)d_in[3];
    const float* inv_temp  = (const float*)d_in[4];
    const float* embedding = (const float*)d_in[5];
    const float* pos_emb   = (const float*)d_in[6];
    const float* Wq        = (const float*)d_in[7];
    const float* bq        = (const float*)d_in[8];
    const float* Wk        = (const float*)d_in[9];
    const float* bk        = (const float*)d_in[10];
    const float* Wv        = (const float*)d_in[11];
    const float* bv        = (const float*)d_in[12];
    const float* Wo        = (const float*)d_in[13];
    const float* bo        = (const float*)d_in[14];
    const float* ln1_g     = (const float*)d_in[15];
    const float* ln1_b     = (const float*)d_in[16];
    const float* W1        = (const float*)d_in[17];
    const float* b1        = (const float*)d_in[18];
    const float* W2        = (const float*)d_in[19];
    const float* b2        = (const float*)d_in[20];
    const float* ln2_g     = (const float*)d_in[21];
    const float* ln2_b     = (const float*)d_in[22];
    const float* normf_g   = (const float*)d_in[23];
    const float* normf_b   = (const float*)d_in[24];
    const float* Wout      = (const float*)d_in[25];
    const float* bout      = (const float*)d_in[26];

    float* ws = (float*)d_ws;
    const size_t M1 = (size_t)N_ * D_;          // 2097152
    float* x    = ws;                            // [0, 1*M1)
    float* qf   = ws + 1 * M1;                   // [1,2)
    float* kf   = ws + 2 * M1;                   // [2,3)
    float* vb   = ws + 3 * M1;                   // [3,4)
    float* att  = ws + 4 * M1;                   // [4,5)
    float* res  = ws + 5 * M1;                   // [5,6)
    float* h1   = ws + 1 * M1;                   // FFN hidden aliases qf..att
    float* cs   = ws + 6 * M1;                   // B*H*NC*64*64 = 1048576
    float* sb   = ws + 6 * M1 + 1048576;
    float* ksc  = ws + 6 * M1 + 2097152;         // 16384
    float* ksb  = ksc + 16384;
    float* cosT = ksb + 16384;                   // 32768
    float* sinT = cosT + 32768;                  // total ~14.8M floats (~59MB)

    float* out_f = (float*)d_out;
    float* og_f  = out_f + (size_t)N_ * V_;

    embed_k<<<2048, 256, 0, stream>>>(inputs, embedding, pos_emb, x);
    ropetab_k<<<128, 256, 0, stream>>>(cosT, sinT);

    for (int l = 0; l < L_; ++l) {
        const float* Wql = Wq + (size_t)l * D_ * D_;
        const float* Wkl = Wk + (size_t)l * D_ * D_;
        const float* Wvl = Wv + (size_t)l * D_ * D_;
        const float* Wol = Wo + (size_t)l * D_ * D_;
        const float* W1l = W1 + (size_t)l * D_ * FF_;
        const float* W2l = W2 + (size_t)l * FF_ * D_;

        launch_gemm(EPI_BIAS, x, Wql, bq + (size_t)l * D_, nullptr, qf, N_, D_, D_, stream);
        launch_gemm(EPI_BIAS, x, Wkl, bk + (size_t)l * D_, nullptr, kf, N_, D_, D_, stream);
        launch_gemm(EPI_BIAS, x, Wvl, bv + (size_t)l * D_, nullptr, vb, N_, D_, D_, stream);
        rope_elu_k<<<4096, 256, 0, stream>>>(qf, kf, cosT, sinT, mask);
        attn_chunksum_k<<<B_ * H_ * NC, 256, 0, stream>>>(kf, vb, cs, ksc);
        attn_prefix_k<<<B_ * H_, 256, 0, stream>>>(cs, ksc, sb, ksb);
        attn_out_k<<<B_ * H_ * NC, 256, 0, stream>>>(qf, kf, vb, sb, ksb, att);
        launch_gemm(EPI_BIAS_RES, att, Wol, bo + (size_t)l * D_, x, res, N_, D_, D_, stream);
        cln_k<<<N_, 256, 0, stream>>>(res, x, ln1_g + (size_t)l * COND_ * D_,
                                      ln1_b + (size_t)l * COND_ * D_, cond);
        launch_gemm(EPI_BIAS_GELU, x, W1l, b1 + (size_t)l * FF_, nullptr, h1, N_, FF_, D_, stream);
        launch_gemm(EPI_BIAS_RES, h1, W2l, b2 + (size_t)l * D_, x, res, N_, D_, FF_, stream);
        cln_k<<<N_, 256, 0, stream>>>(res, x, ln2_g + (size_t)l * COND_ * D_,
                                      ln2_b + (size_t)l * COND_ * D_, cond);
    }

    cln_k<<<N_, 256, 0, stream>>>(x, res, normf_g, normf_b, cond);
    launch_gemm(EPI_BIAS, res, Wout, bout, nullptr, out_f, N_, V_, D_, stream);
    gumbel_k<<<N_, 256, 0, stream>>>(out_f, gumbel_u, inv_temp, og_f);
}